// Round 8
// baseline (708.567 us; speedup 1.0000x reference)
//
#include <hip/hip_runtime.h>
#include <math.h>

namespace {

constexpr int N = 100000;   // nodes
constexpr int E = 1600000;  // edges
constexpr int G = 2000;     // graphs
constexpr int L = 2000;     // links

constexpr int SCAN_CHUNK = 1024;                       // elements per block
constexpr int NB = (N + SCAN_CHUNK - 1) / SCAN_CHUNK;  // 98 scan blocks

constexpr int NXCD = 8;
constexpr int NP = N / NXCD;  // 12500 nodes per partition (N % 8 == 0)

// ---------------- CSR build (XCD-partitioned) ----------------

__global__ void hist_part_kernel(const int* __restrict__ dst, int* __restrict__ deg) {
  const int part = blockIdx.x & (NXCD - 1);
  const int lo = part * NP;
  const int hi = lo + NP;
  const int bidp = blockIdx.x >> 3;
  const int stridev = (gridDim.x >> 3) * blockDim.x;  // int4 stride
  const int nvec = E >> 2;                            // E % 4 == 0
  for (int v = bidp * blockDim.x + threadIdx.x; v < nvec; v += stridev) {
    const int4 d4 = *reinterpret_cast<const int4*>(dst + v * 4);
    if (d4.x >= lo && d4.x < hi) atomicAdd(&deg[d4.x], 1);
    if (d4.y >= lo && d4.y < hi) atomicAdd(&deg[d4.y], 1);
    if (d4.z >= lo && d4.z < hi) atomicAdd(&deg[d4.z], 1);
    if (d4.w >= lo && d4.w < hi) atomicAdd(&deg[d4.w], 1);
  }
}

__global__ void fill_part_kernel(const int* __restrict__ src, const int* __restrict__ dst,
                                 int* __restrict__ cursor, int* __restrict__ col) {
  const int part = blockIdx.x & (NXCD - 1);
  const int lo = part * NP;
  const int hi = lo + NP;
  const int bidp = blockIdx.x >> 3;
  const int stridev = (gridDim.x >> 3) * blockDim.x;
  const int nvec = E >> 2;
  for (int v = bidp * blockDim.x + threadIdx.x; v < nvec; v += stridev) {
    const int e = v * 4;
    const int4 d4 = *reinterpret_cast<const int4*>(dst + e);
    if (d4.x >= lo && d4.x < hi) col[atomicAdd(&cursor[d4.x], 1)] = src[e];
    if (d4.y >= lo && d4.y < hi) col[atomicAdd(&cursor[d4.y], 1)] = src[e + 1];
    if (d4.z >= lo && d4.z < hi) col[atomicAdd(&cursor[d4.z], 1)] = src[e + 2];
    if (d4.w >= lo && d4.w < hi) col[atomicAdd(&cursor[d4.w], 1)] = src[e + 3];
  }
}

// pass 1: per-block sums of deg
__global__ void scan1_kernel(const int* __restrict__ deg, int* __restrict__ bsum) {
  const int t = threadIdx.x;
  const int base = blockIdx.x * SCAN_CHUNK + t * 4;
  int s = 0;
  if (base < N) {
    const int4 v = *reinterpret_cast<const int4*>(deg + base);
    s = v.x + v.y + v.z + v.w;
  }
  __shared__ int ss[256];
  ss[t] = s;
  __syncthreads();
#pragma unroll
  for (int off = 128; off >= 1; off >>= 1) {
    if (t < off) ss[t] += ss[t + off];
    __syncthreads();
  }
  if (t == 0) bsum[blockIdx.x] = ss[0];
}

// pass 2: exclusive scan of the NB block sums
__global__ void scan2_kernel(const int* __restrict__ bsum, int* __restrict__ boff) {
  __shared__ int ss[128];
  const int t = threadIdx.x;
  ss[t] = (t < NB) ? bsum[t] : 0;
  __syncthreads();
#pragma unroll
  for (int off = 1; off < 128; off <<= 1) {
    int v = (t >= off) ? ss[t - off] : 0;
    __syncthreads();
    ss[t] += v;
    __syncthreads();
  }
  if (t < NB) boff[t] = (t == 0) ? 0 : ss[t - 1];
}

// pass 3: local scan + offset -> row_ptr & cursor; dis = rsqrt(deg+1)
__global__ void scan3_kernel(const int* __restrict__ deg, const int* __restrict__ boff,
                             int* __restrict__ row_ptr, int* __restrict__ cursor,
                             float* __restrict__ dis) {
  const int t = threadIdx.x;
  const int base = blockIdx.x * SCAN_CHUNK + t * 4;
  int d0 = 0, d1 = 0, d2 = 0, d3 = 0;
  if (base < N) {
    const int4 v = *reinterpret_cast<const int4*>(deg + base);
    d0 = v.x; d1 = v.y; d2 = v.z; d3 = v.w;
  }
  const int tsum = d0 + d1 + d2 + d3;
  __shared__ int ss[256];
  ss[t] = tsum;
  __syncthreads();
#pragma unroll
  for (int off = 1; off < 256; off <<= 1) {
    int v = (t >= off) ? ss[t - off] : 0;
    __syncthreads();
    ss[t] += v;
    __syncthreads();
  }
  if (base < N) {
    const int p0 = ((t == 0) ? 0 : ss[t - 1]) + boff[blockIdx.x];
    const int p1 = p0 + d0;
    const int p2 = p1 + d1;
    const int p3 = p2 + d2;
    *reinterpret_cast<int4*>(row_ptr + base) = make_int4(p0, p1, p2, p3);
    *reinterpret_cast<int4*>(cursor + base) = make_int4(p0, p1, p2, p3);
    const float4 dv = make_float4(rsqrtf((float)d0 + 1.0f), rsqrtf((float)d1 + 1.0f),
                                  rsqrtf((float)d2 + 1.0f), rsqrtf((float)d3 + 1.0f));
    *reinterpret_cast<float4*>(dis + base) = dv;
  }
  if (blockIdx.x == 0 && t == 0) row_ptr[N] = E;
}

// ---------------- dual GEMM: hd = (x@W)*dis[row], r = x@Wr ----------------

__device__ __forceinline__ void f4fma(float4& a, float s, const float4 w) {
  a.x = fmaf(s, w.x, a.x);
  a.y = fmaf(s, w.y, a.y);
  a.z = fmaf(s, w.z, a.z);
  a.w = fmaf(s, w.w, a.w);
}

template <int FI, int FO>
__global__ __launch_bounds__(1024) void gemm2_kernel(const float* __restrict__ x,
                                                     const float* __restrict__ W,
                                                     const float* __restrict__ Wr,
                                                     const float* __restrict__ dis,
                                                     float* __restrict__ hd,
                                                     float* __restrict__ r) {
  __shared__ float sW[FI * FO];
  __shared__ float sWr[FI * FO];
  for (int i = threadIdx.x; i < FI * FO; i += blockDim.x) {
    sW[i] = W[i];
    sWr[i] = Wr[i];
  }
  __syncthreads();
  constexpr int CG = FO / 4;            // col groups
  const int total = (N / 4) * CG;       // N % 4 == 0
  const int stride = gridDim.x * blockDim.x;
  for (int idx = blockIdx.x * blockDim.x + threadIdx.x; idx < total; idx += stride) {
    const int rb = idx / CG;
    const int col = (idx - rb * CG) * 4;
    const int row0 = rb * 4;
    float4 aH[4], aR[4];
#pragma unroll
    for (int i = 0; i < 4; ++i) {
      aH[i] = make_float4(0.f, 0.f, 0.f, 0.f);
      aR[i] = make_float4(0.f, 0.f, 0.f, 0.f);
    }
    const float* xr = x + (size_t)row0 * FI;
#pragma unroll
    for (int k = 0; k < FI; k += 4) {
      float xs[4][4];
#pragma unroll
      for (int i = 0; i < 4; ++i) {
        const float4 xv = *reinterpret_cast<const float4*>(xr + i * FI + k);
        xs[i][0] = xv.x; xs[i][1] = xv.y; xs[i][2] = xv.z; xs[i][3] = xv.w;
      }
#pragma unroll
      for (int kk = 0; kk < 4; ++kk) {
        const float4 w4 = *reinterpret_cast<const float4*>(&sW[(k + kk) * FO + col]);
        const float4 w4r = *reinterpret_cast<const float4*>(&sWr[(k + kk) * FO + col]);
#pragma unroll
        for (int i = 0; i < 4; ++i) {
          f4fma(aH[i], xs[i][kk], w4);
          f4fma(aR[i], xs[i][kk], w4r);
        }
      }
    }
    const float4 dv = *reinterpret_cast<const float4*>(dis + row0);
    const float dl[4] = {dv.x, dv.y, dv.z, dv.w};
#pragma unroll
    for (int i = 0; i < 4; ++i) {
      float4 o = aH[i];
      o.x *= dl[i]; o.y *= dl[i]; o.z *= dl[i]; o.w *= dl[i];
      *reinterpret_cast<float4*>(&hd[(size_t)(row0 + i) * FO + col]) = o;
      *reinterpret_cast<float4*>(&r[(size_t)(row0 + i) * FO + col]) = aR[i];
    }
  }
}

// ---------------- fused CSR gather + self-loop + residual + LN + ReLU ----------------
// float4 gathers: FO/4 lanes per node, each lane owns 4 features.
// Per edge: FO/4 x dwordx4 loads (16B/lane) -> 4x bytes per VMEM queue slot.

template <int FO, bool POOL>
__global__ void gcn_agg_kernel(const int* __restrict__ row_ptr, const int* __restrict__ col,
                               const float* __restrict__ hd, const float* __restrict__ r,
                               const float* __restrict__ dis,
                               const float* __restrict__ b, const float* __restrict__ br,
                               const float* __restrict__ g, const float* __restrict__ bt,
                               float* __restrict__ out, const int* __restrict__ batch,
                               float* __restrict__ gemb, float* __restrict__ cnt) {
  constexpr int NL = FO / 4;    // lanes per node
  constexpr int NPW = 64 / NL;  // nodes per wave (N % NPW == 0)
  const int lane = threadIdx.x & 63;
  const int q = lane & (NL - 1);        // feature-quad index within node
  const int sub = lane / NL;            // node slot within wave
  const int f0 = q * 4;                 // first feature owned by this lane
  const int waveId = (blockIdx.x * blockDim.x + threadIdx.x) >> 6;
  const int nWaves = (gridDim.x * blockDim.x) >> 6;
  const int nGroups = N / NPW;
  const float4 b4 = *reinterpret_cast<const float4*>(b + f0);
  const float4 br4 = *reinterpret_cast<const float4*>(br + f0);
  const float4 g4 = *reinterpret_cast<const float4*>(g + f0);
  const float4 bt4 = *reinterpret_cast<const float4*>(bt + f0);
  const float cb0 = b4.x + br4.x, cb1 = b4.y + br4.y, cb2 = b4.z + br4.z, cb3 = b4.w + br4.w;
  for (int w = waveId; w < nGroups; w += nWaves) {
    const int node = w * NPW + sub;
    const int beg = row_ptr[node];
    const int end = row_ptr[node + 1];
    float4 a0 = make_float4(0.f, 0.f, 0.f, 0.f);
    float4 a1 = a0, a2 = a0, a3 = a0;
    int k = beg;
    const int end4 = beg + ((end - beg) & ~3);
    for (; k < end4; k += 4) {
      const int s0 = col[k];
      const int s1 = col[k + 1];
      const int s2 = col[k + 2];
      const int s3 = col[k + 3];
      const float4 v0 = *reinterpret_cast<const float4*>(hd + (size_t)s0 * FO + f0);
      const float4 v1 = *reinterpret_cast<const float4*>(hd + (size_t)s1 * FO + f0);
      const float4 v2 = *reinterpret_cast<const float4*>(hd + (size_t)s2 * FO + f0);
      const float4 v3 = *reinterpret_cast<const float4*>(hd + (size_t)s3 * FO + f0);
      a0.x += v0.x; a0.y += v0.y; a0.z += v0.z; a0.w += v0.w;
      a1.x += v1.x; a1.y += v1.y; a1.z += v1.z; a1.w += v1.w;
      a2.x += v2.x; a2.y += v2.y; a2.z += v2.z; a2.w += v2.w;
      a3.x += v3.x; a3.y += v3.y; a3.z += v3.z; a3.w += v3.w;
    }
    for (; k < end; ++k) {
      const float4 v = *reinterpret_cast<const float4*>(hd + (size_t)col[k] * FO + f0);
      a0.x += v.x; a0.y += v.y; a0.z += v.z; a0.w += v.w;
    }
    const float acc0 = (a0.x + a1.x) + (a2.x + a3.x);
    const float acc1 = (a0.y + a1.y) + (a2.y + a3.y);
    const float acc2 = (a0.z + a1.z) + (a2.z + a3.z);
    const float acc3 = (a0.w + a1.w) + (a2.w + a3.w);
    const float dv = dis[node];
    const size_t base = (size_t)node * FO + f0;
    const float4 sh = *reinterpret_cast<const float4*>(hd + base);
    const float4 rr = *reinterpret_cast<const float4*>(r + base);
    float v0 = fmaf(dv, acc0 + sh.x, cb0 + rr.x);
    float v1 = fmaf(dv, acc1 + sh.y, cb1 + rr.y);
    float v2 = fmaf(dv, acc2 + sh.z, cb2 + rr.z);
    float v3 = fmaf(dv, acc3 + sh.w, cb3 + rr.w);
    // mean over FO: intra-lane sum of 4 + shfl over NL lanes
    float s = (v0 + v1) + (v2 + v3);
#pragma unroll
    for (int m = NL / 2; m >= 1; m >>= 1) s += __shfl_xor(s, m, 64);
    const float mean = s * (1.0f / FO);
    const float d0 = v0 - mean, d1 = v1 - mean, d2 = v2 - mean, d3 = v3 - mean;
    float vs = (d0 * d0 + d1 * d1) + (d2 * d2 + d3 * d3);
#pragma unroll
    for (int m = NL / 2; m >= 1; m >>= 1) vs += __shfl_xor(vs, m, 64);
    const float rs = rsqrtf(vs * (1.0f / FO) + 1e-5f);
    float o0 = fmaxf(d0 * rs * g4.x + bt4.x, 0.f);
    float o1 = fmaxf(d1 * rs * g4.y + bt4.y, 0.f);
    float o2 = fmaxf(d2 * rs * g4.z + bt4.z, 0.f);
    float o3 = fmaxf(d3 * rs * g4.w + bt4.w, 0.f);
    if (POOL) {
      const int bb = batch[node];
      atomicAdd(&gemb[bb * FO + f0 + 0], o0);
      atomicAdd(&gemb[bb * FO + f0 + 1], o1);
      atomicAdd(&gemb[bb * FO + f0 + 2], o2);
      atomicAdd(&gemb[bb * FO + f0 + 3], o3);
      if (q == 0) atomicAdd(&cnt[bb], 1.0f);
    } else {
      *reinterpret_cast<float4*>(out + base) = make_float4(o0, o1, o2, o3);
    }
  }
}

// ---------------- pool normalize + link MLP ----------------

__global__ void gdiv_kernel(float* __restrict__ gemb, const float* __restrict__ cnt) {
  const int idx = blockIdx.x * blockDim.x + threadIdx.x;
  if (idx < G * 16) gemb[idx] /= fmaxf(cnt[idx >> 4], 1.0f);
}

__global__ void mlp_kernel(const float* __restrict__ gemb, const int* __restrict__ link,
                           const float* __restrict__ Wm1, const float* __restrict__ bm1,
                           const float* __restrict__ Wm2, const float* __restrict__ bm2,
                           const float* __restrict__ Wm3, const float* __restrict__ bm3,
                           float* __restrict__ out) {
  __shared__ float sW1[32 * 16], sW2[16 * 8], sW3[8], sb1[16], sb2[8], sb3;
  for (int i = threadIdx.x; i < 32 * 16; i += blockDim.x) sW1[i] = Wm1[i];
  for (int i = threadIdx.x; i < 16 * 8; i += blockDim.x) sW2[i] = Wm2[i];
  if (threadIdx.x < 8) {
    sW3[threadIdx.x] = Wm3[threadIdx.x];
    sb2[threadIdx.x] = bm2[threadIdx.x];
  }
  if (threadIdx.x < 16) sb1[threadIdx.x] = bm1[threadIdx.x];
  if (threadIdx.x == 0) sb3 = bm3[0];
  __syncthreads();
  const int l = blockIdx.x * blockDim.x + threadIdx.x;
  if (l >= L) return;
  const int a = link[l];
  const int c = link[L + l];
  float feat[32];
#pragma unroll
  for (int k = 0; k < 16; ++k) feat[k] = gemb[a * 16 + k];
#pragma unroll
  for (int k = 0; k < 16; ++k) feat[16 + k] = gemb[c * 16 + k];
  float z1[16];
#pragma unroll
  for (int j = 0; j < 16; ++j) {
    float s = sb1[j];
#pragma unroll
    for (int k = 0; k < 32; ++k) s = fmaf(feat[k], sW1[k * 16 + j], s);
    z1[j] = fmaxf(s, 0.f);
  }
  float z2[8];
#pragma unroll
  for (int j = 0; j < 8; ++j) {
    float s = sb2[j];
#pragma unroll
    for (int k = 0; k < 16; ++k) s = fmaf(z1[k], sW2[k * 8 + j], s);
    z2[j] = fmaxf(s, 0.f);
  }
  float z3 = sb3;
#pragma unroll
  for (int k = 0; k < 8; ++k) z3 = fmaf(z2[k], sW3[k], z3);
  out[l] = 1.f / (1.f + expf(-z3));
}

}  // namespace

extern "C" void kernel_launch(void* const* d_in, const int* in_sizes, int n_in,
                              void* d_out, int out_size, void* d_ws, size_t ws_size,
                              hipStream_t stream) {
  (void)in_sizes; (void)n_in; (void)out_size; (void)ws_size;
  const float* x = (const float*)d_in[0];
  const int* src = (const int*)d_in[1];
  const int* dst = (const int*)d_in[2];
  const int* batch = (const int*)d_in[3];
  const int* link = (const int*)d_in[4];
  const float *Wl[4], *bl[4], *Wrl[4], *brl[4], *gl[4], *btl[4];
  for (int i = 0; i < 4; ++i) {
    Wl[i] = (const float*)d_in[5 + 6 * i + 0];
    bl[i] = (const float*)d_in[5 + 6 * i + 1];
    Wrl[i] = (const float*)d_in[5 + 6 * i + 2];
    brl[i] = (const float*)d_in[5 + 6 * i + 3];
    gl[i] = (const float*)d_in[5 + 6 * i + 4];
    btl[i] = (const float*)d_in[5 + 6 * i + 5];
  }
  const float* Wm1 = (const float*)d_in[29];
  const float* bm1 = (const float*)d_in[30];
  const float* Wm2 = (const float*)d_in[31];
  const float* bm2 = (const float*)d_in[32];
  const float* Wm3 = (const float*)d_in[33];
  const float* bm3 = (const float*)d_in[34];
  float* out = (float*)d_out;

  // workspace layout (4B units):
  char* wsb = (char*)d_ws;
  int* deg_i = (int*)wsb;                      // N
  int* row_ptr = deg_i + N;                    // N+1
  int* cursor = row_ptr + (N + 1);             // N
  float* dis = (float*)(cursor + N);           // N
  int* bsum = (int*)(dis + N);                 // NB
  int* boff = bsum + NB;                       // NB
  int* col = boff + NB;                        // E
  float* bufA = (float*)(col + E);             // N*64 (hd)
  float* bufB = bufA + (size_t)N * 64;         // N*64 (r)
  float* bufC = bufB + (size_t)N * 64;         // N*64 (layer io)
  float* gemb = bufC + (size_t)N * 64;         // G*16
  float* cnt = gemb + (size_t)G * 16;          // G

  // ---- CSR build + normalization (XCD-partitioned hist/fill) ----
  hipMemsetAsync(deg_i, 0, N * sizeof(int), stream);
  hist_part_kernel<<<2048, 256, 0, stream>>>(dst, deg_i);
  scan1_kernel<<<NB, 256, 0, stream>>>(deg_i, bsum);
  scan2_kernel<<<1, 128, 0, stream>>>(bsum, boff);
  scan3_kernel<<<NB, 256, 0, stream>>>(deg_i, boff, row_ptr, cursor, dis);
  fill_part_kernel<<<2048, 256, 0, stream>>>(src, dst, cursor, col);

  const int AGG_BLOCKS = 2048;

  // Layer 1: 128 -> 64
  gemm2_kernel<128, 64><<<((N / 4) * 16 + 1023) / 1024, 1024, 0, stream>>>(x, Wl[0], Wrl[0], dis, bufA, bufB);
  gcn_agg_kernel<64, false><<<AGG_BLOCKS, 256, 0, stream>>>(row_ptr, col, bufA, bufB, dis,
                                                            bl[0], brl[0], gl[0], btl[0], bufC,
                                                            batch, gemb, cnt);
  // Layer 2: 64 -> 32
  gemm2_kernel<64, 32><<<((N / 4) * 8 + 1023) / 1024, 1024, 0, stream>>>(bufC, Wl[1], Wrl[1], dis, bufA, bufB);
  gcn_agg_kernel<32, false><<<AGG_BLOCKS, 256, 0, stream>>>(row_ptr, col, bufA, bufB, dis,
                                                            bl[1], brl[1], gl[1], btl[1], bufC,
                                                            batch, gemb, cnt);
  // Layer 3: 32 -> 16
  gemm2_kernel<32, 16><<<((N / 4) * 4 + 1023) / 1024, 1024, 0, stream>>>(bufC, Wl[2], Wrl[2], dis, bufA, bufB);
  gcn_agg_kernel<16, false><<<AGG_BLOCKS, 256, 0, stream>>>(row_ptr, col, bufA, bufB, dis,
                                                            bl[2], brl[2], gl[2], btl[2], bufC,
                                                            batch, gemb, cnt);
  // Layer 4: 16 -> 16, pool fused into epilogue
  hipMemsetAsync(gemb, 0, (size_t)(G * 16 + G) * sizeof(float), stream);
  gemm2_kernel<16, 16><<<((N / 4) * 4 + 1023) / 1024, 1024, 0, stream>>>(bufC, Wl[3], Wrl[3], dis, bufA, bufB);
  gcn_agg_kernel<16, true><<<AGG_BLOCKS, 256, 0, stream>>>(row_ptr, col, bufA, bufB, dis,
                                                           bl[3], brl[3], gl[3], btl[3], nullptr,
                                                           batch, gemb, cnt);
  // pool normalize + link MLP
  gdiv_kernel<<<(G * 16 + 255) / 256, 256, 0, stream>>>(gemb, cnt);
  mlp_kernel<<<(L + 255) / 256, 256, 0, stream>>>(gemb, link, Wm1, bm1, Wm2, bm2, Wm3, bm3, out);
}

// Round 9
// 628.341 us; speedup vs baseline: 1.1277x; 1.1277x over previous
//
#include <hip/hip_runtime.h>
#include <math.h>

namespace {

constexpr int N = 100000;   // nodes
constexpr int E = 1600000;  // edges
constexpr int G = 2000;     // graphs
constexpr int L = 2000;     // links

constexpr int SCAN_CHUNK = 1024;                       // elements per block
constexpr int NB = (N + SCAN_CHUNK - 1) / SCAN_CHUNK;  // 98 scan blocks

constexpr int NXCD = 8;
constexpr int NP = N / NXCD;  // 12500 nodes per partition (N % 8 == 0)

// bf16 helpers (RNE pack, exact unpack)
__device__ __forceinline__ float bf2f(unsigned short u) {
  union { unsigned int i; float f; } v;
  v.i = ((unsigned int)u) << 16;
  return v.f;
}
__device__ __forceinline__ unsigned short f2bf(float f) {
  union { float f; unsigned int i; } v;
  v.f = f;
  const unsigned int x = v.i;
  return (unsigned short)((x + 0x7FFFu + ((x >> 16) & 1u)) >> 16);
}

// ---------------- CSR build (XCD-partitioned) ----------------
// partition = blockIdx & 7 -> under round-robin block->XCD dispatch all blocks
// of a partition share an XCD; deg/cursor/col lines stay in that L2.

__global__ void hist_part_kernel(const int* __restrict__ dst, int* __restrict__ deg) {
  const int part = blockIdx.x & (NXCD - 1);
  const int lo = part * NP;
  const int hi = lo + NP;
  const int bidp = blockIdx.x >> 3;
  const int stridev = (gridDim.x >> 3) * blockDim.x;  // int4 stride
  const int nvec = E >> 2;                            // E % 4 == 0
  for (int v = bidp * blockDim.x + threadIdx.x; v < nvec; v += stridev) {
    const int4 d4 = *reinterpret_cast<const int4*>(dst + v * 4);
    if (d4.x >= lo && d4.x < hi) atomicAdd(&deg[d4.x], 1);
    if (d4.y >= lo && d4.y < hi) atomicAdd(&deg[d4.y], 1);
    if (d4.z >= lo && d4.z < hi) atomicAdd(&deg[d4.z], 1);
    if (d4.w >= lo && d4.w < hi) atomicAdd(&deg[d4.w], 1);
  }
}

__global__ void fill_part_kernel(const int* __restrict__ src, const int* __restrict__ dst,
                                 int* __restrict__ cursor, int* __restrict__ col) {
  const int part = blockIdx.x & (NXCD - 1);
  const int lo = part * NP;
  const int hi = lo + NP;
  const int bidp = blockIdx.x >> 3;
  const int stridev = (gridDim.x >> 3) * blockDim.x;
  const int nvec = E >> 2;
  for (int v = bidp * blockDim.x + threadIdx.x; v < nvec; v += stridev) {
    const int e = v * 4;
    const int4 d4 = *reinterpret_cast<const int4*>(dst + e);
    if (d4.x >= lo && d4.x < hi) col[atomicAdd(&cursor[d4.x], 1)] = src[e];
    if (d4.y >= lo && d4.y < hi) col[atomicAdd(&cursor[d4.y], 1)] = src[e + 1];
    if (d4.z >= lo && d4.z < hi) col[atomicAdd(&cursor[d4.z], 1)] = src[e + 2];
    if (d4.w >= lo && d4.w < hi) col[atomicAdd(&cursor[d4.w], 1)] = src[e + 3];
  }
}

// pass 1: per-block sums of deg
__global__ void scan1_kernel(const int* __restrict__ deg, int* __restrict__ bsum) {
  const int t = threadIdx.x;
  const int base = blockIdx.x * SCAN_CHUNK + t * 4;
  int s = 0;
  if (base < N) {
    const int4 v = *reinterpret_cast<const int4*>(deg + base);
    s = v.x + v.y + v.z + v.w;
  }
  __shared__ int ss[256];
  ss[t] = s;
  __syncthreads();
#pragma unroll
  for (int off = 128; off >= 1; off >>= 1) {
    if (t < off) ss[t] += ss[t + off];
    __syncthreads();
  }
  if (t == 0) bsum[blockIdx.x] = ss[0];
}

// pass 2: exclusive scan of the NB block sums
__global__ void scan2_kernel(const int* __restrict__ bsum, int* __restrict__ boff) {
  __shared__ int ss[128];
  const int t = threadIdx.x;
  ss[t] = (t < NB) ? bsum[t] : 0;
  __syncthreads();
#pragma unroll
  for (int off = 1; off < 128; off <<= 1) {
    int v = (t >= off) ? ss[t - off] : 0;
    __syncthreads();
    ss[t] += v;
    __syncthreads();
  }
  if (t < NB) boff[t] = (t == 0) ? 0 : ss[t - 1];
}

// pass 3: local scan + offset -> row_ptr & cursor; dis = rsqrt(deg+1)
__global__ void scan3_kernel(const int* __restrict__ deg, const int* __restrict__ boff,
                             int* __restrict__ row_ptr, int* __restrict__ cursor,
                             float* __restrict__ dis) {
  const int t = threadIdx.x;
  const int base = blockIdx.x * SCAN_CHUNK + t * 4;
  int d0 = 0, d1 = 0, d2 = 0, d3 = 0;
  if (base < N) {
    const int4 v = *reinterpret_cast<const int4*>(deg + base);
    d0 = v.x; d1 = v.y; d2 = v.z; d3 = v.w;
  }
  const int tsum = d0 + d1 + d2 + d3;
  __shared__ int ss[256];
  ss[t] = tsum;
  __syncthreads();
#pragma unroll
  for (int off = 1; off < 256; off <<= 1) {
    int v = (t >= off) ? ss[t - off] : 0;
    __syncthreads();
    ss[t] += v;
    __syncthreads();
  }
  if (base < N) {
    const int p0 = ((t == 0) ? 0 : ss[t - 1]) + boff[blockIdx.x];
    const int p1 = p0 + d0;
    const int p2 = p1 + d1;
    const int p3 = p2 + d2;
    *reinterpret_cast<int4*>(row_ptr + base) = make_int4(p0, p1, p2, p3);
    *reinterpret_cast<int4*>(cursor + base) = make_int4(p0, p1, p2, p3);
    const float4 dv = make_float4(rsqrtf((float)d0 + 1.0f), rsqrtf((float)d1 + 1.0f),
                                  rsqrtf((float)d2 + 1.0f), rsqrtf((float)d3 + 1.0f));
    *reinterpret_cast<float4*>(dis + base) = dv;
  }
  if (blockIdx.x == 0 && t == 0) row_ptr[N] = E;
}

// ---------------- dual GEMM: hdb = bf16((x@W)*dis[row]), r = x@Wr ----------------

__device__ __forceinline__ void f4fma(float4& a, float s, const float4 w) {
  a.x = fmaf(s, w.x, a.x);
  a.y = fmaf(s, w.y, a.y);
  a.z = fmaf(s, w.z, a.z);
  a.w = fmaf(s, w.w, a.w);
}

template <int FI, int FO>
__global__ __launch_bounds__(1024) void gemm2_kernel(const float* __restrict__ x,
                                                     const float* __restrict__ W,
                                                     const float* __restrict__ Wr,
                                                     const float* __restrict__ dis,
                                                     unsigned short* __restrict__ hdb,
                                                     float* __restrict__ r) {
  __shared__ float sW[FI * FO];
  __shared__ float sWr[FI * FO];
  for (int i = threadIdx.x; i < FI * FO; i += blockDim.x) {
    sW[i] = W[i];
    sWr[i] = Wr[i];
  }
  __syncthreads();
  constexpr int CG = FO / 4;            // col groups
  const int total = (N / 4) * CG;       // N % 4 == 0
  const int stride = gridDim.x * blockDim.x;
  for (int idx = blockIdx.x * blockDim.x + threadIdx.x; idx < total; idx += stride) {
    const int rb = idx / CG;
    const int col = (idx - rb * CG) * 4;
    const int row0 = rb * 4;
    float4 aH[4], aR[4];
#pragma unroll
    for (int i = 0; i < 4; ++i) {
      aH[i] = make_float4(0.f, 0.f, 0.f, 0.f);
      aR[i] = make_float4(0.f, 0.f, 0.f, 0.f);
    }
    const float* xr = x + (size_t)row0 * FI;
#pragma unroll
    for (int k = 0; k < FI; k += 4) {
      float xs[4][4];
#pragma unroll
      for (int i = 0; i < 4; ++i) {
        const float4 xv = *reinterpret_cast<const float4*>(xr + i * FI + k);
        xs[i][0] = xv.x; xs[i][1] = xv.y; xs[i][2] = xv.z; xs[i][3] = xv.w;
      }
#pragma unroll
      for (int kk = 0; kk < 4; ++kk) {
        const float4 w4 = *reinterpret_cast<const float4*>(&sW[(k + kk) * FO + col]);
        const float4 w4r = *reinterpret_cast<const float4*>(&sWr[(k + kk) * FO + col]);
#pragma unroll
        for (int i = 0; i < 4; ++i) {
          f4fma(aH[i], xs[i][kk], w4);
          f4fma(aR[i], xs[i][kk], w4r);
        }
      }
    }
    const float4 dv = *reinterpret_cast<const float4*>(dis + row0);
    const float dl[4] = {dv.x, dv.y, dv.z, dv.w};
#pragma unroll
    for (int i = 0; i < 4; ++i) {
      ushort4 ob;
      ob.x = f2bf(aH[i].x * dl[i]);
      ob.y = f2bf(aH[i].y * dl[i]);
      ob.z = f2bf(aH[i].z * dl[i]);
      ob.w = f2bf(aH[i].w * dl[i]);
      *reinterpret_cast<ushort4*>(&hdb[(size_t)(row0 + i) * FO + col]) = ob;
      *reinterpret_cast<float4*>(&r[(size_t)(row0 + i) * FO + col]) = aR[i];
    }
  }
}

// ---------------- fused CSR gather + self-loop + residual + LN + ReLU ----------------
// Round-7 structure (1 node per FO-lane subgroup, scalar gathers, 4-way unroll)
// with bf16 gathered operand: 2B/lane -> half the 64B sectors per edge.

template <int FO, bool POOL>
__global__ void gcn_agg_kernel(const int* __restrict__ row_ptr, const int* __restrict__ col,
                               const unsigned short* __restrict__ hdb, const float* __restrict__ r,
                               const float* __restrict__ dis,
                               const float* __restrict__ b, const float* __restrict__ br,
                               const float* __restrict__ g, const float* __restrict__ bt,
                               float* __restrict__ out, const int* __restrict__ batch,
                               float* __restrict__ gemb, float* __restrict__ cnt) {
  constexpr int NPW = 64 / FO;  // nodes per wave (N % NPW == 0)
  const int lane = threadIdx.x & 63;
  const int f = lane & (FO - 1);
  const int sub = lane / FO;
  const int waveId = (blockIdx.x * blockDim.x + threadIdx.x) >> 6;
  const int nWaves = (gridDim.x * blockDim.x) >> 6;
  const int nGroups = N / NPW;
  const float bf = b[f], brf = br[f], gf = g[f], btf = bt[f];
  for (int w = waveId; w < nGroups; w += nWaves) {
    const int node = w * NPW + sub;
    const int beg = row_ptr[node];
    const int end = row_ptr[node + 1];
    float a0 = 0.f, a1 = 0.f, a2 = 0.f, a3 = 0.f;
    int k = beg;
    const int end4 = beg + ((end - beg) & ~3);
    for (; k < end4; k += 4) {
      const int s0 = col[k];
      const int s1 = col[k + 1];
      const int s2 = col[k + 2];
      const int s3 = col[k + 3];
      a0 += bf2f(hdb[(size_t)s0 * FO + f]);
      a1 += bf2f(hdb[(size_t)s1 * FO + f]);
      a2 += bf2f(hdb[(size_t)s2 * FO + f]);
      a3 += bf2f(hdb[(size_t)s3 * FO + f]);
    }
    for (; k < end; ++k) a0 += bf2f(hdb[(size_t)col[k] * FO + f]);
    const float acc = (a0 + a1) + (a2 + a3);
    const float dv = dis[node];
    const size_t base = (size_t)node * FO + f;
    const float v = fmaf(dv, acc + bf2f(hdb[base]), bf + r[base] + brf);
    float s = v;
#pragma unroll
    for (int m = FO / 2; m >= 1; m >>= 1) s += __shfl_xor(s, m, 64);
    const float mean = s * (1.0f / FO);
    const float d0 = v - mean;
    float vs = d0 * d0;
#pragma unroll
    for (int m = FO / 2; m >= 1; m >>= 1) vs += __shfl_xor(vs, m, 64);
    const float var = vs * (1.0f / FO);
    float o = d0 * rsqrtf(var + 1e-5f) * gf + btf;
    o = fmaxf(o, 0.f);
    if (POOL) {
      const int bb = batch[node];
      atomicAdd(&gemb[bb * FO + f], o);
      if (f == 0) atomicAdd(&cnt[bb], 1.0f);
    } else {
      out[base] = o;
    }
  }
}

// ---------------- pool normalize + link MLP ----------------

__global__ void gdiv_kernel(float* __restrict__ gemb, const float* __restrict__ cnt) {
  const int idx = blockIdx.x * blockDim.x + threadIdx.x;
  if (idx < G * 16) gemb[idx] /= fmaxf(cnt[idx >> 4], 1.0f);
}

__global__ void mlp_kernel(const float* __restrict__ gemb, const int* __restrict__ link,
                           const float* __restrict__ Wm1, const float* __restrict__ bm1,
                           const float* __restrict__ Wm2, const float* __restrict__ bm2,
                           const float* __restrict__ Wm3, const float* __restrict__ bm3,
                           float* __restrict__ out) {
  __shared__ float sW1[32 * 16], sW2[16 * 8], sW3[8], sb1[16], sb2[8], sb3;
  for (int i = threadIdx.x; i < 32 * 16; i += blockDim.x) sW1[i] = Wm1[i];
  for (int i = threadIdx.x; i < 16 * 8; i += blockDim.x) sW2[i] = Wm2[i];
  if (threadIdx.x < 8) {
    sW3[threadIdx.x] = Wm3[threadIdx.x];
    sb2[threadIdx.x] = bm2[threadIdx.x];
  }
  if (threadIdx.x < 16) sb1[threadIdx.x] = bm1[threadIdx.x];
  if (threadIdx.x == 0) sb3 = bm3[0];
  __syncthreads();
  const int l = blockIdx.x * blockDim.x + threadIdx.x;
  if (l >= L) return;
  const int a = link[l];
  const int c = link[L + l];
  float feat[32];
#pragma unroll
  for (int k = 0; k < 16; ++k) feat[k] = gemb[a * 16 + k];
#pragma unroll
  for (int k = 0; k < 16; ++k) feat[16 + k] = gemb[c * 16 + k];
  float z1[16];
#pragma unroll
  for (int j = 0; j < 16; ++j) {
    float s = sb1[j];
#pragma unroll
    for (int k = 0; k < 32; ++k) s = fmaf(feat[k], sW1[k * 16 + j], s);
    z1[j] = fmaxf(s, 0.f);
  }
  float z2[8];
#pragma unroll
  for (int j = 0; j < 8; ++j) {
    float s = sb2[j];
#pragma unroll
    for (int k = 0; k < 16; ++k) s = fmaf(z1[k], sW2[k * 8 + j], s);
    z2[j] = fmaxf(s, 0.f);
  }
  float z3 = sb3;
#pragma unroll
  for (int k = 0; k < 8; ++k) z3 = fmaf(z2[k], sW3[k], z3);
  out[l] = 1.f / (1.f + expf(-z3));
}

}  // namespace

extern "C" void kernel_launch(void* const* d_in, const int* in_sizes, int n_in,
                              void* d_out, int out_size, void* d_ws, size_t ws_size,
                              hipStream_t stream) {
  (void)in_sizes; (void)n_in; (void)out_size; (void)ws_size;
  const float* x = (const float*)d_in[0];
  const int* src = (const int*)d_in[1];
  const int* dst = (const int*)d_in[2];
  const int* batch = (const int*)d_in[3];
  const int* link = (const int*)d_in[4];
  const float *Wl[4], *bl[4], *Wrl[4], *brl[4], *gl[4], *btl[4];
  for (int i = 0; i < 4; ++i) {
    Wl[i] = (const float*)d_in[5 + 6 * i + 0];
    bl[i] = (const float*)d_in[5 + 6 * i + 1];
    Wrl[i] = (const float*)d_in[5 + 6 * i + 2];
    brl[i] = (const float*)d_in[5 + 6 * i + 3];
    gl[i] = (const float*)d_in[5 + 6 * i + 4];
    btl[i] = (const float*)d_in[5 + 6 * i + 5];
  }
  const float* Wm1 = (const float*)d_in[29];
  const float* bm1 = (const float*)d_in[30];
  const float* Wm2 = (const float*)d_in[31];
  const float* bm2 = (const float*)d_in[32];
  const float* Wm3 = (const float*)d_in[33];
  const float* bm3 = (const float*)d_in[34];
  float* out = (float*)d_out;

  // workspace layout (4B units unless noted):
  char* wsb = (char*)d_ws;
  int* deg_i = (int*)wsb;                      // N
  int* row_ptr = deg_i + N;                    // N+1
  int* cursor = row_ptr + (N + 1);             // N
  float* dis = (float*)(cursor + N);           // N
  int* bsum = (int*)(dis + N);                 // NB
  int* boff = bsum + NB;                       // NB
  int* col = boff + NB;                        // E
  unsigned short* hdb = (unsigned short*)(col + E);  // N*64 bf16
  float* bufB = (float*)(hdb + (size_t)N * 64);      // N*64 (r)
  float* bufC = bufB + (size_t)N * 64;               // N*64 (layer io)
  float* gemb = bufC + (size_t)N * 64;               // G*16
  float* cnt = gemb + (size_t)G * 16;                // G

  // ---- CSR build + normalization (XCD-partitioned hist/fill) ----
  hipMemsetAsync(deg_i, 0, N * sizeof(int), stream);
  hist_part_kernel<<<2048, 256, 0, stream>>>(dst, deg_i);
  scan1_kernel<<<NB, 256, 0, stream>>>(deg_i, bsum);
  scan2_kernel<<<1, 128, 0, stream>>>(bsum, boff);
  scan3_kernel<<<NB, 256, 0, stream>>>(deg_i, boff, row_ptr, cursor, dis);
  fill_part_kernel<<<2048, 256, 0, stream>>>(src, dst, cursor, col);

  const int AGG_BLOCKS = 2048;

  // Layer 1: 128 -> 64
  gemm2_kernel<128, 64><<<((N / 4) * 16 + 1023) / 1024, 1024, 0, stream>>>(x, Wl[0], Wrl[0], dis, hdb, bufB);
  gcn_agg_kernel<64, false><<<AGG_BLOCKS, 256, 0, stream>>>(row_ptr, col, hdb, bufB, dis,
                                                            bl[0], brl[0], gl[0], btl[0], bufC,
                                                            batch, gemb, cnt);
  // Layer 2: 64 -> 32
  gemm2_kernel<64, 32><<<((N / 4) * 8 + 1023) / 1024, 1024, 0, stream>>>(bufC, Wl[1], Wrl[1], dis, hdb, bufB);
  gcn_agg_kernel<32, false><<<AGG_BLOCKS, 256, 0, stream>>>(row_ptr, col, hdb, bufB, dis,
                                                            bl[1], brl[1], gl[1], btl[1], bufC,
                                                            batch, gemb, cnt);
  // Layer 3: 32 -> 16
  gemm2_kernel<32, 16><<<((N / 4) * 4 + 1023) / 1024, 1024, 0, stream>>>(bufC, Wl[2], Wrl[2], dis, hdb, bufB);
  gcn_agg_kernel<16, false><<<AGG_BLOCKS, 256, 0, stream>>>(row_ptr, col, hdb, bufB, dis,
                                                            bl[2], brl[2], gl[2], btl[2], bufC,
                                                            batch, gemb, cnt);
  // Layer 4: 16 -> 16, pool fused into epilogue
  hipMemsetAsync(gemb, 0, (size_t)(G * 16 + G) * sizeof(float), stream);
  gemm2_kernel<16, 16><<<((N / 4) * 4 + 1023) / 1024, 1024, 0, stream>>>(bufC, Wl[3], Wrl[3], dis, hdb, bufB);
  gcn_agg_kernel<16, true><<<AGG_BLOCKS, 256, 0, stream>>>(row_ptr, col, hdb, bufB, dis,
                                                           bl[3], brl[3], gl[3], btl[3], nullptr,
                                                           batch, gemb, cnt);
  // pool normalize + link MLP
  gdiv_kernel<<<(G * 16 + 255) / 256, 256, 0, stream>>>(gemb, cnt);
  mlp_kernel<<<(L + 255) / 256, 256, 0, stream>>>(gemb, link, Wm1, bm1, Wm2, bm2, Wm3, bm3, out);
}